// Round 1
// baseline (375.369 us; speedup 1.0000x reference)
//
#include <hip/hip_runtime.h>
#include <cstddef>

#define TW64 0.09817477042468103f   // 2*pi/64

// complex MAC: acc += v * (c, s)   (w=(c,s) treated as a true complex number;
// forward kernels pass s = -sin so the same formula does e^{-i...})
#define CMAC(A, V)                                   \
    A.x = fmaf((V).x, c, A.x); A.x = fmaf(-(V).y, s, A.x); \
    A.y = fmaf((V).x, s, A.y); A.y = fmaf((V).y, c, A.y);

#define ROT()                                        \
    { float _t0 = s * ss; float _cn = fmaf(c, cs, -_t0); \
      s = fmaf(s, cs, c * ss); c = _cn; }

// ---------------------------------------------------------------------------
// 1) fwd t-DFT: x[blk= b*16c+..*64+x][yy][t] real -> z1[blk][kz][yy]
//    8192 blocks x 192 threads; thread = (k, yg), 4 yy per thread
//    pad 68 floats/row (272B = 17*16) so rows stay 16B-aligned -> float4 LDS IO
__global__ __launch_bounds__(192) void k_fwd_t(const float* __restrict__ x,
                                               float2* __restrict__ z1) {
    __shared__ __align__(16) float xs[64 * 68];      // [yy][t] pad 68
    __shared__ __align__(16) float2 tmp[768];        // [k][yy]
    const int tid = threadIdx.x, blk = blockIdx.x;
    const float4* src4 = (const float4*)(x + (size_t)blk * 4096);
    for (int i = tid; i < 1024; i += 192) {
        float4 v = src4[i];
        int row = i >> 4, c4 = i & 15;
        *(float4*)&xs[row * 68 + c4 * 4] = v;
    }
    __syncthreads();
    const int k = tid % 12, yg = tid / 12;      // yg 0..15
    const float* r0 = xs + (yg     ) * 68;
    const float* r1 = xs + (yg + 16) * 68;
    const float* r2 = xs + (yg + 32) * 68;
    const float* r3 = xs + (yg + 48) * 68;
    float ss, cs; __sincosf(-(float)k * TW64, &ss, &cs);   // (cos, -sin)
    float c = 1.f, s = 0.f;
    float2 a0 = {0.f,0.f}, a1 = {0.f,0.f}, a2 = {0.f,0.f}, a3 = {0.f,0.f};
    #pragma unroll 4
    for (int t4 = 0; t4 < 16; ++t4) {
        float4 v0 = *(const float4*)(r0 + 4 * t4);
        float4 v1 = *(const float4*)(r1 + 4 * t4);
        float4 v2 = *(const float4*)(r2 + 4 * t4);
        float4 v3 = *(const float4*)(r3 + 4 * t4);
        a0.x = fmaf(v0.x, c, a0.x); a0.y = fmaf(v0.x, s, a0.y);
        a1.x = fmaf(v1.x, c, a1.x); a1.y = fmaf(v1.x, s, a1.y);
        a2.x = fmaf(v2.x, c, a2.x); a2.y = fmaf(v2.x, s, a2.y);
        a3.x = fmaf(v3.x, c, a3.x); a3.y = fmaf(v3.x, s, a3.y);
        ROT();
        a0.x = fmaf(v0.y, c, a0.x); a0.y = fmaf(v0.y, s, a0.y);
        a1.x = fmaf(v1.y, c, a1.x); a1.y = fmaf(v1.y, s, a1.y);
        a2.x = fmaf(v2.y, c, a2.x); a2.y = fmaf(v2.y, s, a2.y);
        a3.x = fmaf(v3.y, c, a3.x); a3.y = fmaf(v3.y, s, a3.y);
        ROT();
        a0.x = fmaf(v0.z, c, a0.x); a0.y = fmaf(v0.z, s, a0.y);
        a1.x = fmaf(v1.z, c, a1.x); a1.y = fmaf(v1.z, s, a1.y);
        a2.x = fmaf(v2.z, c, a2.x); a2.y = fmaf(v2.z, s, a2.y);
        a3.x = fmaf(v3.z, c, a3.x); a3.y = fmaf(v3.z, s, a3.y);
        ROT();
        a0.x = fmaf(v0.w, c, a0.x); a0.y = fmaf(v0.w, s, a0.y);
        a1.x = fmaf(v1.w, c, a1.x); a1.y = fmaf(v1.w, s, a1.y);
        a2.x = fmaf(v2.w, c, a2.x); a2.y = fmaf(v2.w, s, a2.y);
        a3.x = fmaf(v3.w, c, a3.x); a3.y = fmaf(v3.w, s, a3.y);
        ROT();
    }
    tmp[k * 64 + yg     ] = a0;
    tmp[k * 64 + yg + 16] = a1;
    tmp[k * 64 + yg + 32] = a2;
    tmp[k * 64 + yg + 48] = a3;
    __syncthreads();
    float4* dst4 = (float4*)(z1 + (size_t)blk * 768);
    const float4* tp4 = (const float4*)tmp;
    for (int i = tid; i < 384; i += 192) dst4[i] = tp4[i];
}

// ---------------------------------------------------------------------------
// 2) fwd y-DFT: z1[(bc*64+xx)][kz][yy] -> z2[(bc*64+xx)][ky][kz]
//    blk = bc*32+xh (2 xx per block); 4096 blocks x 192 threads
//    thread = (sub, ky, g): one recurrence (step ky), 3 kz outputs
__global__ __launch_bounds__(192) void k_fwd_y(const float2* __restrict__ z1,
                                               float2* __restrict__ z2) {
    __shared__ __align__(16) float2 zs[2 * 792];     // [sub][kz][yy] pad 66
    __shared__ __align__(16) float2 tmp[576];        // [sub][ky][kz]
    const int tid = threadIdx.x, blk = blockIdx.x;
    const float4* src4 = (const float4*)(z1 + (size_t)blk * 1536);
    for (int i = tid; i < 768; i += 192) {
        float4 v = src4[i];
        int sb = i / 384, rem = (i % 384) * 2;       // first float2 index in 768
        *(float4*)&zs[sb * 792 + (rem >> 6) * 66 + (rem & 63)] = v;
    }
    __syncthreads();
    const int sub = tid / 96, r = tid % 96;
    const int ky = r % 24, g = r / 24;                 // g 0..3
    const int kya = (ky < 12) ? ky : ky + 40;
    const float2* p0 = zs + sub * 792 + (g    ) * 66;
    const float2* p1 = zs + sub * 792 + (g + 4) * 66;
    const float2* p2 = zs + sub * 792 + (g + 8) * 66;
    float ss, cs; __sincosf(-(float)kya * TW64, &ss, &cs);
    float c = 1.f, s = 0.f;
    float2 a0 = {0.f,0.f}, a1 = {0.f,0.f}, a2 = {0.f,0.f};
    #pragma unroll 4
    for (int yy = 0; yy < 64; ++yy) {
        float2 v0 = p0[yy], v1 = p1[yy], v2 = p2[yy];
        CMAC(a0, v0); CMAC(a1, v1); CMAC(a2, v2);
        ROT();
    }
    tmp[sub * 288 + ky * 12 + g    ] = a0;
    tmp[sub * 288 + ky * 12 + g + 4] = a1;
    tmp[sub * 288 + ky * 12 + g + 8] = a2;
    __syncthreads();
    float4* dst4 = (float4*)(z2 + (size_t)blk * 576);
    const float4* tp4 = (const float4*)tmp;
    for (int i = tid; i < 288; i += 192) dst4[i] = tp4[i];
}

// ---------------------------------------------------------------------------
// 3) fwd x-DFT: z2[(bc*64+xx)][ky][kz] -> z3[bc][kx][ky][kz]
//    blk = bc*12+kyh (2 ky per block); 1536 blocks x 192 threads
__global__ __launch_bounds__(192) void k_fwd_x(const float2* __restrict__ z2,
                                               float2* __restrict__ z3) {
    __shared__ __align__(16) float2 zs[2 * 792];     // [sub(ky)][kz][xx] pad 66
    __shared__ __align__(16) float2 tmp[576];        // [kx][sub][kz]
    const int tid = threadIdx.x, blk = blockIdx.x;
    const int kyh = blk % 12, bc = blk / 12;
    const float2* srcb = z2 + (size_t)bc * 18432 + (size_t)kyh * 24;
    for (int f = tid; f < 768; f += 192) {
        int xx = f / 12, r2 = f % 12;
        int sb = r2 / 6, kzp = (r2 % 6) * 2;
        float4 v = *(const float4*)&srcb[(size_t)xx * 288 + sb * 12 + kzp];
        zs[sb * 792 + (kzp    ) * 66 + xx] = make_float2(v.x, v.y);
        zs[sb * 792 + (kzp + 1) * 66 + xx] = make_float2(v.z, v.w);
    }
    __syncthreads();
    const int sub = tid / 96, r = tid % 96;
    const int kx = r % 24, g = r / 24;
    const int kxa = (kx < 12) ? kx : kx + 40;
    const float2* p0 = zs + sub * 792 + (g    ) * 66;
    const float2* p1 = zs + sub * 792 + (g + 4) * 66;
    const float2* p2 = zs + sub * 792 + (g + 8) * 66;
    float ss, cs; __sincosf(-(float)kxa * TW64, &ss, &cs);
    float c = 1.f, s = 0.f;
    float2 a0 = {0.f,0.f}, a1 = {0.f,0.f}, a2 = {0.f,0.f};
    #pragma unroll 4
    for (int xx = 0; xx < 64; ++xx) {
        float2 v0 = p0[xx], v1 = p1[xx], v2 = p2[xx];
        CMAC(a0, v0); CMAC(a1, v1); CMAC(a2, v2);
        ROT();
    }
    tmp[kx * 24 + sub * 12 + g    ] = a0;
    tmp[kx * 24 + sub * 12 + g + 4] = a1;
    tmp[kx * 24 + sub * 12 + g + 8] = a2;
    __syncthreads();
    float2* dstb = z3 + (size_t)bc * 6912 + (size_t)kyh * 24;
    for (int f = tid; f < 288; f += 192) {
        int row = f / 12, c2 = (f % 12) * 2;
        *(float4*)&dstb[(size_t)row * 288 + c2] = *(const float4*)&tmp[row * 24 + c2];
    }
}

// ---------------------------------------------------------------------------
// 4) channel mix: z3[b*16+ci][kx][ky][kz] -> z4[(b*16+o)][ky][kx][kz]
//    blk = kx*24+ky (576 blocks) x 192 threads; weights in regs, b-loop inside
__global__ __launch_bounds__(192) void k_mix(const float2* __restrict__ z3,
                                             const float* __restrict__ w1,
                                             const float* __restrict__ w2,
                                             const float* __restrict__ w3,
                                             const float* __restrict__ w4,
                                             float2* __restrict__ z4) {
    __shared__ __align__(16) float2 zs[12 * 17];     // [kz][ci] pad 17
    const int tid = threadIdx.x, blk = blockIdx.x;
    const int ky = blk % 24, kx = blk / 24;
    const int o = tid / 12, kz = tid % 12;
    const float* wsel = (kx < 12) ? ((ky < 12) ? w1 : w3) : ((ky < 12) ? w2 : w4);
    const int mx = (kx < 12) ? kx : kx - 12;
    const int my = (ky < 12) ? ky : ky - 12;
    const float* wp = wsel + (size_t)2 * (((o * 12 + mx) * 12 + my) * 12 + kz);
    float wr[16], wi[16];
    #pragma unroll
    for (int i = 0; i < 16; ++i) {
        wr[i] = wp[0]; wi[i] = wp[1];
        wp += 2 * 16 * 12 * 12 * 12;
    }
    for (int b = 0; b < 8; ++b) {
        __syncthreads();
        {   // loader view: tid -> (ci, kz2)
            int ci = tid / 12, kz2 = tid % 12;
            zs[kz2 * 17 + ci] =
                z3[((size_t)(b * 16 + ci) * 24 + kx) * 288 + ky * 12 + kz2];
        }
        __syncthreads();
        float re = 0.f, im = 0.f;
        #pragma unroll
        for (int i = 0; i < 16; ++i) {
            float2 a = zs[kz * 17 + i];
            re = fmaf(a.x, wr[i], re); re = fmaf(-a.y, wi[i], re);
            im = fmaf(a.x, wi[i], im); im = fmaf(a.y, wr[i], im);
        }
        z4[((size_t)(b * 16 + o) * 24 + ky) * 288 + kx * 12 + kz] =
            make_float2(re, im);
    }
}

// ---------------------------------------------------------------------------
// 5) inv x-DFT: z4[bo][ky][kx][kz] -> z5[bo][ky][kz][xx]
//    blk = bo*24+ky (3072) x 256 threads; thread = (xx, g): 1 recurrence, 3 kz
__global__ __launch_bounds__(256) void k_inv_x(const float2* __restrict__ z4,
                                               float2* __restrict__ z5) {
    __shared__ __align__(16) float2 zs[12 * 26];     // [kz][kx] pad 26
    const int tid = threadIdx.x, blk = blockIdx.x;
    const float2* src = z4 + (size_t)blk * 288;
    for (int f = tid; f < 144; f += 256) {
        int kx = f / 6, kzp = (f % 6) * 2;
        float4 v = *(const float4*)&src[(size_t)kx * 12 + kzp];
        zs[(kzp    ) * 26 + kx] = make_float2(v.x, v.y);
        zs[(kzp + 1) * 26 + kx] = make_float2(v.z, v.w);
    }
    __syncthreads();
    const int xx = tid & 63, g = tid >> 6;
    const float2* p0 = zs + (g    ) * 26;
    const float2* p1 = zs + (g + 4) * 26;
    const float2* p2 = zs + (g + 8) * 26;
    float ss, cs; __sincosf((float)xx * TW64, &ss, &cs);   // (cos, +sin)
    float c = 1.f, s = 0.f;
    float2 a0 = {0.f,0.f}, a1 = {0.f,0.f}, a2 = {0.f,0.f};
    #pragma unroll 4
    for (int j = 0; j < 12; ++j) {
        float2 v0 = p0[j], v1 = p1[j], v2 = p2[j];
        CMAC(a0, v0); CMAC(a1, v1); CMAC(a2, v2);
        ROT();
    }
    { float sh, ch; __sincosf((float)((52 * xx) & 63) * TW64, &sh, &ch);
      c = ch; s = sh; }
    #pragma unroll 4
    for (int j = 12; j < 24; ++j) {
        float2 v0 = p0[j], v1 = p1[j], v2 = p2[j];
        CMAC(a0, v0); CMAC(a1, v1); CMAC(a2, v2);
        ROT();
    }
    float2* dst = z5 + (size_t)blk * 768;
    dst[(g    ) * 64 + xx] = a0;
    dst[(g + 4) * 64 + xx] = a1;
    dst[(g + 8) * 64 + xx] = a2;
}

// ---------------------------------------------------------------------------
// 6) inv y-DFT: z5[bo][ky][kz][xx] -> z6[bo][xx][yy][kz]
//    blk = bo*64+xx (8192) x 256 threads
__global__ __launch_bounds__(256) void k_inv_y(const float2* __restrict__ z5,
                                               float2* __restrict__ z6) {
    __shared__ __align__(16) float2 zs[12 * 26];     // [kz][ky]
    __shared__ __align__(16) float2 tmp[768];        // [yy][kz]
    const int tid = threadIdx.x, blk = blockIdx.x;
    const int xx = blk & 63, bo = blk >> 6;
    for (int i = tid; i < 288; i += 256) {
        int ky = i / 12, kz = i % 12;
        zs[kz * 26 + ky] = z5[((size_t)bo * 24 + ky) * 768 + kz * 64 + xx];
    }
    __syncthreads();
    const int yy = tid & 63, g = tid >> 6;
    const float2* p0 = zs + (g    ) * 26;
    const float2* p1 = zs + (g + 4) * 26;
    const float2* p2 = zs + (g + 8) * 26;
    float ss, cs; __sincosf((float)yy * TW64, &ss, &cs);
    float c = 1.f, s = 0.f;
    float2 a0 = {0.f,0.f}, a1 = {0.f,0.f}, a2 = {0.f,0.f};
    #pragma unroll 4
    for (int j = 0; j < 12; ++j) {
        float2 v0 = p0[j], v1 = p1[j], v2 = p2[j];
        CMAC(a0, v0); CMAC(a1, v1); CMAC(a2, v2);
        ROT();
    }
    { float sh, ch; __sincosf((float)((52 * yy) & 63) * TW64, &sh, &ch);
      c = ch; s = sh; }
    #pragma unroll 4
    for (int j = 12; j < 24; ++j) {
        float2 v0 = p0[j], v1 = p1[j], v2 = p2[j];
        CMAC(a0, v0); CMAC(a1, v1); CMAC(a2, v2);
        ROT();
    }
    tmp[yy * 12 + g    ] = a0;
    tmp[yy * 12 + g + 4] = a1;
    tmp[yy * 12 + g + 8] = a2;
    __syncthreads();
    float4* dst4 = (float4*)(z6 + (size_t)blk * 768);
    const float4* tp4 = (const float4*)tmp;
    for (int i = tid; i < 384; i += 256) dst4[i] = tp4[i];
}

// ---------------------------------------------------------------------------
// 7) irfft over t + 1/64^3 + ReLU + 16x16 channel mix + bias
//    blk = b*1024 + xx*16 + yq (8192) x 256 threads (4 yy per block, thread=(sub,t))
__global__ __launch_bounds__(256) void k_inv_t_mix(const float2* __restrict__ z6,
                                                   const float* __restrict__ low,
                                                   const float* __restrict__ lob,
                                                   float* __restrict__ out) {
    __shared__ __align__(16) float2 zr[4 * 192];     // [sub][o][kz]
    __shared__ float lws[256];
    __shared__ float lbs[16];
    const int tid = threadIdx.x, blk = blockIdx.x;
    const int yq = blk & 15, xx = (blk >> 4) & 63, b = blk >> 10;
    for (int f = tid; f < 384; f += 256) {
        int sb = f / 96, rem = (f % 96) * 2;         // rem = float2 idx in 192
        int o = rem / 12, kz = rem % 12;
        int yy = yq * 4 + sb;
        *(float4*)&zr[f * 2] =
            *(const float4*)&z6[((size_t)(b * 16 + o) * 4096 + xx * 64 + yy) * 12 + kz];
    }
    lws[tid & 255] = low[tid & 255];
    if (tid < 16) lbs[tid] = lob[tid];
    __syncthreads();
    const int sub = tid >> 6, t = tid & 63;
    const float2* zp = zr + sub * 192;
    float bs, bc; __sincosf((float)t * TW64, &bs, &bc);
    const float inv = 1.0f / 262144.0f;
    float cw[12], sw[12];
    cw[0] = inv; sw[0] = 0.f;
    {
        float c = bc, s = bs;
        #pragma unroll
        for (int k = 1; k < 12; ++k) {
            cw[k] = 2.f * inv * c; sw[k] = 2.f * inv * s;
            float cn = c * bc - s * bs;
            s = fmaf(s, bc, c * bs);
            c = cn;
        }
    }
    float r[16];
    #pragma unroll
    for (int o = 0; o < 16; ++o) {
        float v = 0.f;
        #pragma unroll
        for (int k = 0; k < 12; ++k) {
            float2 a = zp[o * 12 + k];
            v = fmaf(a.x, cw[k], v);
            v = fmaf(-a.y, sw[k], v);
        }
        r[o] = fmaxf(v, 0.f);
    }
    const int yy = yq * 4 + sub;
    const size_t obase = (size_t)b * 16 * 262144 + (size_t)xx * 4096
                       + (size_t)yy * 64 + t;
    #pragma unroll
    for (int op = 0; op < 16; ++op) {
        float acc = lbs[op];
        #pragma unroll
        for (int c2 = 0; c2 < 16; ++c2) acc = fmaf(lws[op * 16 + c2], r[c2], acc);
        out[obase + (size_t)op * 262144] = acc;
    }
}

// ---------------------------------------------------------------------------
extern "C" void kernel_launch(void* const* d_in, const int* in_sizes, int n_in,
                              void* d_out, int out_size, void* d_ws, size_t ws_size,
                              hipStream_t stream) {
    const float* x    = (const float*)d_in[0];
    const float* w1   = (const float*)d_in[1];
    const float* w2   = (const float*)d_in[2];
    const float* w3   = (const float*)d_in[3];
    const float* w4   = (const float*)d_in[4];
    const float* lo_w = (const float*)d_in[5];
    const float* lo_b = (const float*)d_in[6];
    float* out = (float*)d_out;
    char* ws = (char*)d_ws;

    // Workspace (bytes), lifetime-reused, total 96 MB:
    //   z1 [0, 50331648)          dead after k_fwd_y
    //   z2 [50331648, 69206016)   dead after k_fwd_x
    //   z3 [69206016, 76283904)   dead after k_mix
    //   z4 [76283904, 83361792)   dead after k_inv_x
    //   z5 = z1 region (18.9 MB)  born in k_inv_x
    //   z6 [50331648, 100663296)  born in k_inv_y
    float2* z1 = (float2*)(ws);
    float2* z2 = (float2*)(ws + 50331648);
    float2* z3 = (float2*)(ws + 69206016);
    float2* z4 = (float2*)(ws + 76283904);
    float2* z5 = (float2*)(ws);
    float2* z6 = (float2*)(ws + 50331648);

    k_fwd_t    <<<dim3(8192), dim3(192), 0, stream>>>(x, z1);
    k_fwd_y    <<<dim3(4096), dim3(192), 0, stream>>>(z1, z2);
    k_fwd_x    <<<dim3(1536), dim3(192), 0, stream>>>(z2, z3);
    k_mix      <<<dim3(576),  dim3(192), 0, stream>>>(z3, w1, w2, w3, w4, z4);
    k_inv_x    <<<dim3(3072), dim3(256), 0, stream>>>(z4, z5);
    k_inv_y    <<<dim3(8192), dim3(256), 0, stream>>>(z5, z6);
    k_inv_t_mix<<<dim3(8192), dim3(256), 0, stream>>>(z6, lo_w, lo_b, out);
}

// Round 3
// 367.456 us; speedup vs baseline: 1.0215x; 1.0215x over previous
//
#include <hip/hip_runtime.h>
#include <cstddef>

#define TW64 0.09817477042468103f   // 2*pi/64

// complex MAC: acc += v * (c, s)
#define CMAC(A, V)                                   \
    A.x = fmaf((V).x, c, A.x); A.x = fmaf(-(V).y, s, A.x); \
    A.y = fmaf((V).x, s, A.y); A.y = fmaf((V).y, c, A.y);

#define ROT()                                        \
    { float _t0 = s * ss; float _cn = fmaf(c, cs, -_t0); \
      s = fmaf(s, cs, c * ss); c = _cn; }

// ---------------------------------------------------------------------------
// 1) FUSED fwd t-DFT + y-DFT: x[blk=(b*16+ci)*64+xx][yy][t] -> z2[blk][ky][kz]
//    8192 blocks x 192 threads.
//    phase 1: thread=(k,yg), 4 yy rows each, t-recurrence -> tmp[kz][yy]
//    phase 2: threads 0..95 = (ky,g), 3 kz each, yy-recurrence -> obuf[ky][kz]
__global__ __launch_bounds__(192) void k_fwd_ty(const float* __restrict__ x,
                                                float2* __restrict__ z2) {
    __shared__ __align__(16) float  xs[64 * 68];     // [yy][t] pad 68 (16B rows)
    __shared__ __align__(16) float2 tmp[12 * 66];    // [kz][yy] pad 66
    __shared__ __align__(16) float2 obuf[288];       // [ky][kz]
    const int tid = threadIdx.x, blk = blockIdx.x;
    const float4* src4 = (const float4*)(x + (size_t)blk * 4096);
    for (int i = tid; i < 1024; i += 192) {
        float4 v = src4[i];
        int row = i >> 4, c4 = i & 15;
        *(float4*)&xs[row * 68 + c4 * 4] = v;
    }
    __syncthreads();
    // ---- phase 1: t-DFT
    {
        const int k = tid % 12, yg = tid / 12;      // yg 0..15
        const float* r0 = xs + (yg     ) * 68;
        const float* r1 = xs + (yg + 16) * 68;
        const float* r2 = xs + (yg + 32) * 68;
        const float* r3 = xs + (yg + 48) * 68;
        float ss, cs; __sincosf(-(float)k * TW64, &ss, &cs);   // (cos, -sin)
        float c = 1.f, s = 0.f;
        float2 a0 = {0.f,0.f}, a1 = {0.f,0.f}, a2 = {0.f,0.f}, a3 = {0.f,0.f};
        #pragma unroll 4
        for (int t4 = 0; t4 < 16; ++t4) {
            float4 v0 = *(const float4*)(r0 + 4 * t4);
            float4 v1 = *(const float4*)(r1 + 4 * t4);
            float4 v2 = *(const float4*)(r2 + 4 * t4);
            float4 v3 = *(const float4*)(r3 + 4 * t4);
            a0.x = fmaf(v0.x, c, a0.x); a0.y = fmaf(v0.x, s, a0.y);
            a1.x = fmaf(v1.x, c, a1.x); a1.y = fmaf(v1.x, s, a1.y);
            a2.x = fmaf(v2.x, c, a2.x); a2.y = fmaf(v2.x, s, a2.y);
            a3.x = fmaf(v3.x, c, a3.x); a3.y = fmaf(v3.x, s, a3.y);
            ROT();
            a0.x = fmaf(v0.y, c, a0.x); a0.y = fmaf(v0.y, s, a0.y);
            a1.x = fmaf(v1.y, c, a1.x); a1.y = fmaf(v1.y, s, a1.y);
            a2.x = fmaf(v2.y, c, a2.x); a2.y = fmaf(v2.y, s, a2.y);
            a3.x = fmaf(v3.y, c, a3.x); a3.y = fmaf(v3.y, s, a3.y);
            ROT();
            a0.x = fmaf(v0.z, c, a0.x); a0.y = fmaf(v0.z, s, a0.y);
            a1.x = fmaf(v1.z, c, a1.x); a1.y = fmaf(v1.z, s, a1.y);
            a2.x = fmaf(v2.z, c, a2.x); a2.y = fmaf(v2.z, s, a2.y);
            a3.x = fmaf(v3.z, c, a3.x); a3.y = fmaf(v3.z, s, a3.y);
            ROT();
            a0.x = fmaf(v0.w, c, a0.x); a0.y = fmaf(v0.w, s, a0.y);
            a1.x = fmaf(v1.w, c, a1.x); a1.y = fmaf(v1.w, s, a1.y);
            a2.x = fmaf(v2.w, c, a2.x); a2.y = fmaf(v2.w, s, a2.y);
            a3.x = fmaf(v3.w, c, a3.x); a3.y = fmaf(v3.w, s, a3.y);
            ROT();
        }
        tmp[k * 66 + yg     ] = a0;
        tmp[k * 66 + yg + 16] = a1;
        tmp[k * 66 + yg + 32] = a2;
        tmp[k * 66 + yg + 48] = a3;
    }
    __syncthreads();
    // ---- phase 2: y-DFT (96 active threads)
    if (tid < 96) {
        const int ky = tid % 24, g = tid / 24;
        const int kya = (ky < 12) ? ky : ky + 40;
        const float2* p0 = tmp + (g    ) * 66;
        const float2* p1 = tmp + (g + 4) * 66;
        const float2* p2 = tmp + (g + 8) * 66;
        float ss, cs; __sincosf(-(float)kya * TW64, &ss, &cs);
        float c = 1.f, s = 0.f;
        float2 a0 = {0.f,0.f}, a1 = {0.f,0.f}, a2 = {0.f,0.f};
        #pragma unroll 4
        for (int yy = 0; yy < 64; ++yy) {
            float2 v0 = p0[yy], v1 = p1[yy], v2 = p2[yy];
            CMAC(a0, v0); CMAC(a1, v1); CMAC(a2, v2);
            ROT();
        }
        obuf[ky * 12 + g    ] = a0;
        obuf[ky * 12 + g + 4] = a1;
        obuf[ky * 12 + g + 8] = a2;
    }
    __syncthreads();
    float4* dst4 = (float4*)(z2 + (size_t)blk * 288);
    const float4* ob4 = (const float4*)obuf;
    if (tid < 144) dst4[tid] = ob4[tid];
}

// ---------------------------------------------------------------------------
// 2) fwd x-DFT: z2[(bc*64+xx)][ky][kz] -> z3[bc][kx][ky][kz]
//    blk = bc*12+kyh (2 ky per block); 1536 blocks x 192 threads
__global__ __launch_bounds__(192) void k_fwd_x(const float2* __restrict__ z2,
                                               float2* __restrict__ z3) {
    __shared__ __align__(16) float2 zs[2 * 792];     // [sub(ky)][kz][xx] pad 66
    __shared__ __align__(16) float2 tmp[576];        // [kx][sub][kz]
    const int tid = threadIdx.x, blk = blockIdx.x;
    const int kyh = blk % 12, bc = blk / 12;
    const float2* srcb = z2 + (size_t)bc * 18432 + (size_t)kyh * 24;
    for (int f = tid; f < 768; f += 192) {
        int xx = f / 12, r2 = f % 12;
        int sb = r2 / 6, kzp = (r2 % 6) * 2;
        float4 v = *(const float4*)&srcb[(size_t)xx * 288 + sb * 12 + kzp];
        zs[sb * 792 + (kzp    ) * 66 + xx] = make_float2(v.x, v.y);
        zs[sb * 792 + (kzp + 1) * 66 + xx] = make_float2(v.z, v.w);
    }
    __syncthreads();
    const int sub = tid / 96, r = tid % 96;
    const int kx = r % 24, g = r / 24;
    const int kxa = (kx < 12) ? kx : kx + 40;
    const float2* p0 = zs + sub * 792 + (g    ) * 66;
    const float2* p1 = zs + sub * 792 + (g + 4) * 66;
    const float2* p2 = zs + sub * 792 + (g + 8) * 66;
    float ss, cs; __sincosf(-(float)kxa * TW64, &ss, &cs);
    float c = 1.f, s = 0.f;
    float2 a0 = {0.f,0.f}, a1 = {0.f,0.f}, a2 = {0.f,0.f};
    #pragma unroll 4
    for (int xx = 0; xx < 64; ++xx) {
        float2 v0 = p0[xx], v1 = p1[xx], v2 = p2[xx];
        CMAC(a0, v0); CMAC(a1, v1); CMAC(a2, v2);
        ROT();
    }
    tmp[kx * 24 + sub * 12 + g    ] = a0;
    tmp[kx * 24 + sub * 12 + g + 4] = a1;
    tmp[kx * 24 + sub * 12 + g + 8] = a2;
    __syncthreads();
    float2* dstb = z3 + (size_t)bc * 6912 + (size_t)kyh * 24;
    for (int f = tid; f < 288; f += 192) {
        int row = f / 12, c2 = (f % 12) * 2;
        *(float4*)&dstb[(size_t)row * 288 + c2] = *(const float4*)&tmp[row * 24 + c2];
    }
}

// ---------------------------------------------------------------------------
// 3) channel mix: z3[b*16+ci][kx][ky][kz] -> z4[(b*16+o)][ky][kx][kz]
__global__ __launch_bounds__(192) void k_mix(const float2* __restrict__ z3,
                                             const float* __restrict__ w1,
                                             const float* __restrict__ w2,
                                             const float* __restrict__ w3,
                                             const float* __restrict__ w4,
                                             float2* __restrict__ z4) {
    __shared__ __align__(16) float2 zs[12 * 17];     // [kz][ci] pad 17
    const int tid = threadIdx.x, blk = blockIdx.x;
    const int ky = blk % 24, kx = blk / 24;
    const int o = tid / 12, kz = tid % 12;
    const float* wsel = (kx < 12) ? ((ky < 12) ? w1 : w3) : ((ky < 12) ? w2 : w4);
    const int mx = (kx < 12) ? kx : kx - 12;
    const int my = (ky < 12) ? ky : ky - 12;
    const float* wp = wsel + (size_t)2 * (((o * 12 + mx) * 12 + my) * 12 + kz);
    float wr[16], wi[16];
    #pragma unroll
    for (int i = 0; i < 16; ++i) {
        wr[i] = wp[0]; wi[i] = wp[1];
        wp += 2 * 16 * 12 * 12 * 12;
    }
    for (int b = 0; b < 8; ++b) {
        __syncthreads();
        {   // loader view: tid -> (ci, kz2)
            int ci = tid / 12, kz2 = tid % 12;
            zs[kz2 * 17 + ci] =
                z3[((size_t)(b * 16 + ci) * 24 + kx) * 288 + ky * 12 + kz2];
        }
        __syncthreads();
        float re = 0.f, im = 0.f;
        #pragma unroll
        for (int i = 0; i < 16; ++i) {
            float2 a = zs[kz * 17 + i];
            re = fmaf(a.x, wr[i], re); re = fmaf(-a.y, wi[i], re);
            im = fmaf(a.x, wi[i], im); im = fmaf(a.y, wr[i], im);
        }
        z4[((size_t)(b * 16 + o) * 24 + ky) * 288 + kx * 12 + kz] =
            make_float2(re, im);
    }
}

// ---------------------------------------------------------------------------
// 4) inv x-DFT: z4[bo][ky][kx][kz] -> z5[bo][ky][kz][xx]
__global__ __launch_bounds__(256) void k_inv_x(const float2* __restrict__ z4,
                                               float2* __restrict__ z5) {
    __shared__ __align__(16) float2 zs[12 * 26];     // [kz][kx] pad 26
    const int tid = threadIdx.x, blk = blockIdx.x;
    const float2* src = z4 + (size_t)blk * 288;
    for (int f = tid; f < 144; f += 256) {
        int kx = f / 6, kzp = (f % 6) * 2;
        float4 v = *(const float4*)&src[(size_t)kx * 12 + kzp];
        zs[(kzp    ) * 26 + kx] = make_float2(v.x, v.y);
        zs[(kzp + 1) * 26 + kx] = make_float2(v.z, v.w);
    }
    __syncthreads();
    const int xx = tid & 63, g = tid >> 6;
    const float2* p0 = zs + (g    ) * 26;
    const float2* p1 = zs + (g + 4) * 26;
    const float2* p2 = zs + (g + 8) * 26;
    float ss, cs; __sincosf((float)xx * TW64, &ss, &cs);   // (cos, +sin)
    float c = 1.f, s = 0.f;
    float2 a0 = {0.f,0.f}, a1 = {0.f,0.f}, a2 = {0.f,0.f};
    #pragma unroll 4
    for (int j = 0; j < 12; ++j) {
        float2 v0 = p0[j], v1 = p1[j], v2 = p2[j];
        CMAC(a0, v0); CMAC(a1, v1); CMAC(a2, v2);
        ROT();
    }
    { float sh, ch; __sincosf((float)((52 * xx) & 63) * TW64, &sh, &ch);
      c = ch; s = sh; }
    #pragma unroll 4
    for (int j = 12; j < 24; ++j) {
        float2 v0 = p0[j], v1 = p1[j], v2 = p2[j];
        CMAC(a0, v0); CMAC(a1, v1); CMAC(a2, v2);
        ROT();
    }
    float2* dst = z5 + (size_t)blk * 768;
    dst[(g    ) * 64 + xx] = a0;
    dst[(g + 4) * 64 + xx] = a1;
    dst[(g + 8) * 64 + xx] = a2;
}

// ---------------------------------------------------------------------------
// 5) FUSED inv y-DFT + irfft(t) + ReLU + 16x16 mix + bias
//    blk = b*64+xx (512 blocks) x 512 threads
//    stage: zs[o][ky][kz] (36.9 KB)  phase A -> zr[yy][o*12+kz] (97 KB, pad 194)
//    phase B: thread=(yy,tq), 8 t per thread (t = tq+8i)
__global__ __launch_bounds__(512) void k_inv_ty_mix(const float2* __restrict__ z5,
                                                    const float* __restrict__ low,
                                                    const float* __restrict__ lob,
                                                    float* __restrict__ out) {
    __shared__ __align__(16) float2 zs[16 * 288];    // [o][ky][kz]
    __shared__ __align__(16) float2 zr[64 * 194];    // [yy][o*12+kz] pad +2
    __shared__ __align__(16) float  lws[256];
    __shared__ float lbs[16];
    const int tid = threadIdx.x, blk = blockIdx.x;
    const int xx = blk & 63, b = blk >> 6;
    for (int f = tid; f < 4608; f += 512) {
        int o = f / 288, r = f % 288, ky = r / 12, kz = r % 12;
        zs[f] = z5[(size_t)((b * 16 + o) * 24 + ky) * 768 + kz * 64 + xx];
    }
    if (tid < 256) lws[tid] = low[tid];
    if (tid < 16)  lbs[tid] = lob[tid];
    __syncthreads();
    // ---- phase A: inverse y-DFT (all 64 yy). thread = (o, yy8, g); 8 yy, 3 kz.
    {
        const int o = tid >> 5, yy8 = (tid >> 2) & 7, g = tid & 3;
        float cj[8], sj[8], csj[8], ssj[8];
        float2 acc[8][3];
        #pragma unroll
        for (int j = 0; j < 8; ++j) {
            int yyj = yy8 + 8 * j;
            __sincosf((float)yyj * TW64, &ssj[j], &csj[j]);   // step e^{+i yy w}
            cj[j] = 1.f; sj[j] = 0.f;
            acc[j][0] = make_float2(0.f, 0.f);
            acc[j][1] = make_float2(0.f, 0.f);
            acc[j][2] = make_float2(0.f, 0.f);
        }
        const float2* zp = zs + o * 288;
        #pragma unroll 4
        for (int ky = 0; ky < 12; ++ky) {
            float2 v0 = zp[ky * 12 + g];
            float2 v1 = zp[ky * 12 + g + 4];
            float2 v2 = zp[ky * 12 + g + 8];
            #pragma unroll
            for (int j = 0; j < 8; ++j) {
                float c = cj[j], s = sj[j];
                CMAC(acc[j][0], v0); CMAC(acc[j][1], v1); CMAC(acc[j][2], v2);
                float cn = fmaf(c, csj[j], -(s * ssj[j]));
                sj[j] = fmaf(s, csj[j], c * ssj[j]);
                cj[j] = cn;
            }
        }
        #pragma unroll
        for (int j = 0; j < 8; ++j) {           // ky=12 -> kya=52 re-init
            int m = (52 * (yy8 + 8 * j)) & 63;
            __sincosf((float)m * TW64, &sj[j], &cj[j]);
        }
        #pragma unroll 4
        for (int ky = 12; ky < 24; ++ky) {
            float2 v0 = zp[ky * 12 + g];
            float2 v1 = zp[ky * 12 + g + 4];
            float2 v2 = zp[ky * 12 + g + 8];
            #pragma unroll
            for (int j = 0; j < 8; ++j) {
                float c = cj[j], s = sj[j];
                CMAC(acc[j][0], v0); CMAC(acc[j][1], v1); CMAC(acc[j][2], v2);
                float cn = fmaf(c, csj[j], -(s * ssj[j]));
                sj[j] = fmaf(s, csj[j], c * ssj[j]);
                cj[j] = cn;
            }
        }
        #pragma unroll
        for (int j = 0; j < 8; ++j) {
            int yyj = yy8 + 8 * j;
            zr[yyj * 194 + o * 12 + g    ] = acc[j][0];
            zr[yyj * 194 + o * 12 + g + 4] = acc[j][1];
            zr[yyj * 194 + o * 12 + g + 8] = acc[j][2];
        }
    }
    __syncthreads();
    // ---- phase B: irfft(t) + relu + mix.  thread = (yy, tq); t = tq + 8*i.
    const int yy = tid >> 3, tq = tid & 7;
    const float2* zp = zr + yy * 194;
    const float4* lws4 = (const float4*)lws;
    const float inv = 1.0f / 262144.0f;
    const size_t obase = (size_t)b * 16 * 262144 + (size_t)xx * 4096
                       + (size_t)yy * 64;
    #pragma unroll
    for (int b2 = 0; b2 < 2; ++b2) {
        float ci[4], si[4], cti[4], sti[4];
        #pragma unroll
        for (int i = 0; i < 4; ++i) {
            int t = tq + 8 * (4 * b2 + i);
            float sv, cv; __sincosf((float)t * TW64, &sv, &cv);
            cti[i] = cv; sti[i] = sv;
            ci[i] = 2.f * inv * cv; si[i] = 2.f * inv * sv;   // k=1 value
        }
        float acc[4][16];
        #pragma unroll
        for (int o = 0; o < 16; ++o) {          // k = 0 term
            float vx = zp[o * 12].x;
            #pragma unroll
            for (int i = 0; i < 4; ++i) acc[i][o] = inv * vx;
        }
        #pragma unroll 4
        for (int kk = 1; kk < 12; ++kk) {
            float2 v[16];
            #pragma unroll
            for (int o = 0; o < 16; ++o) v[o] = zp[o * 12 + kk];
            #pragma unroll
            for (int i = 0; i < 4; ++i) {
                float c = ci[i], s = si[i];
                #pragma unroll
                for (int o = 0; o < 16; ++o) {
                    acc[i][o] = fmaf(v[o].x, c, acc[i][o]);
                    acc[i][o] = fmaf(-v[o].y, s, acc[i][o]);
                }
                float cn = fmaf(c, cti[i], -(s * sti[i]));
                si[i] = fmaf(s, cti[i], c * sti[i]);
                ci[i] = cn;
            }
        }
        #pragma unroll
        for (int i = 0; i < 4; ++i) {
            #pragma unroll
            for (int o = 0; o < 16; ++o) acc[i][o] = fmaxf(acc[i][o], 0.f);
        }
        #pragma unroll
        for (int op = 0; op < 16; ++op) {
            float4 wa = lws4[op * 4 + 0], wb = lws4[op * 4 + 1];
            float4 wc = lws4[op * 4 + 2], wd = lws4[op * 4 + 3];
            float bias = lbs[op];
            #pragma unroll
            for (int i = 0; i < 4; ++i) {
                float m = bias;
                m = fmaf(wa.x, acc[i][0],  m); m = fmaf(wa.y, acc[i][1],  m);
                m = fmaf(wa.z, acc[i][2],  m); m = fmaf(wa.w, acc[i][3],  m);
                m = fmaf(wb.x, acc[i][4],  m); m = fmaf(wb.y, acc[i][5],  m);
                m = fmaf(wb.z, acc[i][6],  m); m = fmaf(wb.w, acc[i][7],  m);
                m = fmaf(wc.x, acc[i][8],  m); m = fmaf(wc.y, acc[i][9],  m);
                m = fmaf(wc.z, acc[i][10], m); m = fmaf(wc.w, acc[i][11], m);
                m = fmaf(wd.x, acc[i][12], m); m = fmaf(wd.y, acc[i][13], m);
                m = fmaf(wd.z, acc[i][14], m); m = fmaf(wd.w, acc[i][15], m);
                out[obase + (size_t)op * 262144 + (tq + 8 * (4 * b2 + i))] = m;
            }
        }
    }
}

// ---------------------------------------------------------------------------
extern "C" void kernel_launch(void* const* d_in, const int* in_sizes, int n_in,
                              void* d_out, int out_size, void* d_ws, size_t ws_size,
                              hipStream_t stream) {
    const float* x    = (const float*)d_in[0];
    const float* w1   = (const float*)d_in[1];
    const float* w2   = (const float*)d_in[2];
    const float* w3   = (const float*)d_in[3];
    const float* w4   = (const float*)d_in[4];
    const float* lo_w = (const float*)d_in[5];
    const float* lo_b = (const float*)d_in[6];
    float* out = (float*)d_out;
    char* ws = (char*)d_ws;

    // Workspace (bytes), all regions disjoint, total ~52 MB:
    //   z2 [0, 18874368)
    //   z3 [18874368, 25952256)
    //   z4 [25952256, 33030144)
    //   z5 [33030144, 51904512)
    float2* z2 = (float2*)(ws);
    float2* z3 = (float2*)(ws + 18874368);
    float2* z4 = (float2*)(ws + 25952256);
    float2* z5 = (float2*)(ws + 33030144);

    k_fwd_ty    <<<dim3(8192), dim3(192), 0, stream>>>(x, z2);
    k_fwd_x     <<<dim3(1536), dim3(192), 0, stream>>>(z2, z3);
    k_mix       <<<dim3(576),  dim3(192), 0, stream>>>(z3, w1, w2, w3, w4, z4);
    k_inv_x     <<<dim3(3072), dim3(256), 0, stream>>>(z4, z5);
    k_inv_ty_mix<<<dim3(512),  dim3(512), 0, stream>>>(z5, lo_w, lo_b, out);
}